// Round 14
// baseline (597.315 us; speedup 1.0000x reference)
//
#include <hip/hip_runtime.h>

#define BATCH 8
#define CH    48
#define NPTS  4096
#define NBN   (BATCH*NPTS)
#define KNN   9
#define NCAND 12             // per-lane filter depth

typedef unsigned short u16;
typedef unsigned int   u32;
typedef __bf16 bf16x8 __attribute__((ext_vector_type(8)));
typedef float  f32x4  __attribute__((ext_vector_type(4)));

__device__ __forceinline__ float bf2f(u16 v) { return __uint_as_float(((u32)v) << 16); }
__device__ __forceinline__ u16 f2bf(float f) {
  u32 u = __float_as_uint(f);
  u = (u + 0x7fffu + ((u >> 16) & 1u)) >> 16;
  return (u16)u;
}

// ======================= FAST PATH (ws >= ~55 MB) =======================
// k_prep: normalize per reference; write xraw/xn fp32 node-major, csq;
// build hi/lo-split bf16 operands. A layout MFMA-coalesced:
// [tile16][variant(4)][lane(64)][8 bf16]; B [node][128]. Zero deg.
__global__ __launch_bounds__(256)
void k_prep(const float* __restrict__ x, float* __restrict__ xraw,
            float* __restrict__ xn, float* __restrict__ csq,
            u16* __restrict__ Abuf, u16* __restrict__ Bbuf,
            int* __restrict__ deg) {
  int node = blockIdx.x * 256 + threadIdx.x;
  deg[node] = 0;
  int b = node >> 12, n = node & (NPTS - 1);
  const float* xb = x + (size_t)b * CH * NPTS;
  float f[CH];
#pragma unroll
  for (int c = 0; c < CH; ++c) f[c] = xb[(size_t)c * NPTS + n];
  float a0 = 0, a1 = 0, a2 = 0, a3 = 0;
#pragma unroll
  for (int k = 0; k < CH; k += 4) {
    a0 += f[k] * f[k]; a1 += f[k+1] * f[k+1];
    a2 += f[k+2] * f[k+2]; a3 += f[k+3] * f[k+3];
  }
  float nrm = fmaxf(sqrtf((a0 + a1) + (a2 + a3)), 1e-12f);
  float xv[CH];
#pragma unroll
  for (int c = 0; c < CH; ++c) xv[c] = f[c] / nrm;     // true division (ref)
  a0 = a1 = a2 = a3 = 0;
#pragma unroll
  for (int k = 0; k < CH; k += 4) {
    a0 += xv[k] * xv[k]; a1 += xv[k+1] * xv[k+1];
    a2 += xv[k+2] * xv[k+2]; a3 += xv[k+3] * xv[k+3];
  }
  float csqv = (a0 + a1) + (a2 + a3);
  csq[node] = csqv;
  float4* ro = (float4*)(xraw + (size_t)node * CH);
  float4* no = (float4*)(xn   + (size_t)node * CH);
#pragma unroll
  for (int i = 0; i < CH / 4; ++i) {
    ro[i] = make_float4(f[4*i], f[4*i+1], f[4*i+2], f[4*i+3]);
    no[i] = make_float4(xv[4*i], xv[4*i+1], xv[4*i+2], xv[4*i+3]);
  }
  u16 ah[64], al[64];
#pragma unroll
  for (int k = 0; k < CH; ++k) {
    float av = -2.0f * xv[k];
    u16 h = f2bf(av); ah[k] = h; al[k] = f2bf(av - bf2f(h));
  }
  { u16 h = f2bf(csqv); ah[48] = h; al[48] = f2bf(csqv - bf2f(h)); }
#pragma unroll
  for (int k = 49; k < 64; ++k) { ah[k] = 0; al[k] = 0; }
  u16* Bh = Bbuf + (size_t)node * 128;
#pragma unroll
  for (int k = 0; k < CH; ++k) {
    float bv = xv[k];
    u16 h = f2bf(bv); Bh[k] = h; Bh[64 + k] = f2bf(bv - bf2f(h));
  }
  Bh[48] = 0x3F80; Bh[64 + 48] = 0;            // 1.0 bf16 exact
#pragma unroll
  for (int k = 49; k < 64; ++k) { Bh[k] = 0; Bh[64 + k] = 0; }
  u16* Ag = Abuf + (size_t)(node >> 4) * 2048 + (size_t)(node & 15) * 8;
#pragma unroll
  for (int v = 0; v < 4; ++v) {
    const u16* src = (v < 2) ? ah : al;
    int koff = (v & 1) * 32;
#pragma unroll
    for (int q = 0; q < 4; ++q) {
      uint4 pk;
      const u16* s = src + koff + q * 8;
      pk.x = (u32)s[0] | ((u32)s[1] << 16);
      pk.y = (u32)s[2] | ((u32)s[3] << 16);
      pk.z = (u32)s[4] | ((u32)s[5] << 16);
      pk.w = (u32)s[6] | ((u32)s[7] << 16);
      *(uint4*)(Ag + v * 512 + q * 128) = pk;
    }
  }
}

// k_knn_m: wave = 16-row panel; blockIdx.y = column quarter (64 tiles of 16).
// 6 MFMAs/tile (hh,hl,lh). Branchless packed-u32 top-12 in named registers.
// Grid (512,4) x 4 waves = 8192 waves -> 8 waves/SIMD (TLP hides latency).
#define STEP(si) { u32 _lo = min(si, x); x = max(si, x); si = _lo; }
__global__ __launch_bounds__(256, 8)
void k_knn_m(const u16* __restrict__ Abuf, const u16* __restrict__ Bbuf,
             int* __restrict__ candi) {
  int tid = threadIdx.x;
  int lane = tid & 63;
  int quad = lane >> 4, m16 = lane & 15;
  int panel = blockIdx.x * 4 + (tid >> 6);
  int row = panel * 16 + m16;
  int b4096 = row & ~(NPTS - 1);
  int quarter = blockIdx.y;
  int ct0 = quarter * 64;

  const __bf16* Bb = (const __bf16*)Bbuf + (size_t)row * 128;
  bf16x8 bh0 = *(const bf16x8*)(Bb + quad * 8);
  bf16x8 bh1 = *(const bf16x8*)(Bb + 32 + quad * 8);
  bf16x8 bl0 = *(const bf16x8*)(Bb + 64 + quad * 8);
  bf16x8 bl1 = *(const bf16x8*)(Bb + 96 + quad * 8);

  const __bf16* Ag = (const __bf16*)Abuf + (size_t)(b4096 >> 4) * 2048
                     + (size_t)lane * 8;

  u32 s0=~0u,s1=~0u,s2=~0u,s3=~0u,s4=~0u,s5=~0u,
      s6=~0u,s7=~0u,s8=~0u,s9=~0u,s10=~0u,s11=~0u;

  for (int t = 0; t < 64; ++t) {
    int ct = ct0 + t;
    const __bf16* ap = Ag + (size_t)ct * 2048;
    bf16x8 a0 = *(const bf16x8*)(ap);
    bf16x8 a1 = *(const bf16x8*)(ap + 512);
    bf16x8 a2 = *(const bf16x8*)(ap + 1024);
    bf16x8 a3 = *(const bf16x8*)(ap + 1536);
    f32x4 acc = {0.f, 0.f, 0.f, 0.f};
    acc = __builtin_amdgcn_mfma_f32_16x16x32_bf16(a0, bh0, acc, 0, 0, 0);
    acc = __builtin_amdgcn_mfma_f32_16x16x32_bf16(a1, bh1, acc, 0, 0, 0);
    acc = __builtin_amdgcn_mfma_f32_16x16x32_bf16(a0, bl0, acc, 0, 0, 0);
    acc = __builtin_amdgcn_mfma_f32_16x16x32_bf16(a1, bl1, acc, 0, 0, 0);
    acc = __builtin_amdgcn_mfma_f32_16x16x32_bf16(a2, bh0, acc, 0, 0, 0);
    acc = __builtin_amdgcn_mfma_f32_16x16x32_bf16(a3, bh1, acc, 0, 0, 0);
#pragma unroll
    for (int r = 0; r < 4; ++r) {
      u32 u = __float_as_uint(acc[r]);
      u ^= (u32)((int)u >> 31) | 0x80000000u;        // order-preserving map
      u32 x = (u & 0xFFFFFC00u) | (u32)((ct << 2) | r);
      STEP(s0) STEP(s1) STEP(s2) STEP(s3) STEP(s4) STEP(s5)
      STEP(s6) STEP(s7) STEP(s8) STEP(s9) STEP(s10) STEP(s11)
    }
  }

  int* o = candi + (((size_t)row * 4 + quarter) * 4 + quad) * NCAND;
  o[0]  = (int)(((s0  & 0x3FFu) >> 2) * 16 + quad * 4 + (s0  & 3u));
  o[1]  = (int)(((s1  & 0x3FFu) >> 2) * 16 + quad * 4 + (s1  & 3u));
  o[2]  = (int)(((s2  & 0x3FFu) >> 2) * 16 + quad * 4 + (s2  & 3u));
  o[3]  = (int)(((s3  & 0x3FFu) >> 2) * 16 + quad * 4 + (s3  & 3u));
  o[4]  = (int)(((s4  & 0x3FFu) >> 2) * 16 + quad * 4 + (s4  & 3u));
  o[5]  = (int)(((s5  & 0x3FFu) >> 2) * 16 + quad * 4 + (s5  & 3u));
  o[6]  = (int)(((s6  & 0x3FFu) >> 2) * 16 + quad * 4 + (s6  & 3u));
  o[7]  = (int)(((s7  & 0x3FFu) >> 2) * 16 + quad * 4 + (s7  & 3u));
  o[8]  = (int)(((s8  & 0x3FFu) >> 2) * 16 + quad * 4 + (s8  & 3u));
  o[9]  = (int)(((s9  & 0x3FFu) >> 2) * 16 + quad * 4 + (s9  & 3u));
  o[10] = (int)(((s10 & 0x3FFu) >> 2) * 16 + quad * 4 + (s10 & 3u));
  o[11] = (int)(((s11 & 0x3FFu) >> 2) * 16 + quad * 4 + (s11 & 3u));
}

// k_rescore: 16 rows/block x 16 threads/row (1 per candidate list of 12).
// XCD-swizzled block->row map (batch = blockIdx.x & 7) so each XCD's L2
// caches one 786 KB batch window -> gathers become L2 hits. Exact fp32
// rescore, exact (dist,idx) comparator; 2-stage LDS merge. Fused nn write
// + degree histogram (tail edge drop).
#define RR 16
__global__ __launch_bounds__(256, 4)
void k_rescore(const float* __restrict__ xn, const float* __restrict__ csq,
               const int* __restrict__ candi,
               u16* __restrict__ nn, int* __restrict__ deg) {
  __shared__ float md[RR * 16 * KNN];
  __shared__ int   mi[RR * 16 * KNN];
  __shared__ float pd[RR * 4 * KNN];
  __shared__ int   pi[RR * 4 * KNN];
  int tid = threadIdx.x;
  int lr = tid >> 4, q = tid & 15;
  int bi = blockIdx.x;
  int batch = bi & 7, local = bi >> 3;       // XCD swizzle (perf-only)
  int row = batch * NPTS + local * RR + lr;
  int b4096 = row & ~(NPTS - 1);
  const float* xnb = xn + (size_t)b4096 * CH;
  const float* csb = csq + b4096;
  float rf[CH];
  {
    const float4* p = (const float4*)(xn + (size_t)row * CH);
#pragma unroll
    for (int i = 0; i < CH / 4; ++i) {
      float4 v = p[i];
      rf[4*i] = v.x; rf[4*i+1] = v.y; rf[4*i+2] = v.z; rf[4*i+3] = v.w;
    }
  }
  float sqn = csq[row];
  float fd[KNN]; int fi[KNN];
#pragma unroll
  for (int j = 0; j < KNN; ++j) { fd[j] = 3.4e38f; fi[j] = 0x7fffffff; }
  size_t cbase = (((size_t)row * 4 + (q >> 2)) * 4 + (q & 3)) * NCAND;
  for (int s = 0; s < NCAND; ++s) {
    int c = candi[cbase + s] & (NPTS - 1);
    const float4* cp = (const float4*)(xnb + (size_t)c * CH);
    float a0 = 0, a1 = 0, a2 = 0, a3 = 0;
#pragma unroll
    for (int i = 0; i < CH / 4; ++i) {
      float4 v = cp[i];
      a0 += rf[4*i]   * v.x; a1 += rf[4*i+1] * v.y;
      a2 += rf[4*i+2] * v.z; a3 += rf[4*i+3] * v.w;
    }
    float dist = (sqn + csb[c]) - 2.0f * ((a0 + a1) + (a2 + a3));
    if (dist < fd[KNN - 1] || (dist == fd[KNN - 1] && c < fi[KNN - 1])) {
      fd[KNN - 1] = dist; fi[KNN - 1] = c;
#pragma unroll
      for (int k2 = KNN - 1; k2 > 0; --k2) {
        bool sw = (fd[k2] < fd[k2 - 1]) ||
                  (fd[k2] == fd[k2 - 1] && fi[k2] < fi[k2 - 1]);
        if (sw) {
          float td = fd[k2]; fd[k2] = fd[k2 - 1]; fd[k2 - 1] = td;
          int ti = fi[k2]; fi[k2] = fi[k2 - 1]; fi[k2 - 1] = ti;
        }
      }
    }
  }
#pragma unroll
  for (int j = 0; j < KNN; ++j) {
    md[(lr * 16 + q) * KNN + j] = fd[j];
    mi[(lr * 16 + q) * KNN + j] = fi[j];
  }
  __syncthreads();
  if (q < 4) {                       // stage 1: merge lists 4q..4q+3
    float gd[KNN]; int gi[KNN];
#pragma unroll
    for (int j = 0; j < KNN; ++j) { gd[j] = 3.4e38f; gi[j] = 0x7fffffff; }
    for (int l = 0; l < 4; ++l) {
      int s = (lr * 16 + q * 4 + l) * KNN;
      for (int j = 0; j < KNN; ++j) {
        float dc = md[s + j]; int ic = mi[s + j];
        if (dc < gd[KNN - 1] || (dc == gd[KNN - 1] && ic < gi[KNN - 1])) {
          gd[KNN - 1] = dc; gi[KNN - 1] = ic;
#pragma unroll
          for (int k2 = KNN - 1; k2 > 0; --k2) {
            bool sw = (gd[k2] < gd[k2 - 1]) ||
                      (gd[k2] == gd[k2 - 1] && gi[k2] < gi[k2 - 1]);
            if (sw) {
              float td = gd[k2]; gd[k2] = gd[k2 - 1]; gd[k2 - 1] = td;
              int ti = gi[k2]; gi[k2] = gi[k2 - 1]; gi[k2 - 1] = ti;
            }
          }
        }
      }
    }
#pragma unroll
    for (int j = 0; j < KNN; ++j) {
      pd[(lr * 4 + q) * KNN + j] = gd[j];
      pi[(lr * 4 + q) * KNN + j] = gi[j];
    }
  }
  __syncthreads();
  if (q == 0) {                      // stage 2: merge 4 partials
    float gd[KNN]; int gi[KNN];
#pragma unroll
    for (int j = 0; j < KNN; ++j) { gd[j] = 3.4e38f; gi[j] = 0x7fffffff; }
    for (int l = 0; l < 4; ++l) {
      int s = (lr * 4 + l) * KNN;
      for (int j = 0; j < KNN; ++j) {
        float dc = pd[s + j]; int ic = pi[s + j];
        if (dc < gd[KNN - 1] || (dc == gd[KNN - 1] && ic < gi[KNN - 1])) {
          gd[KNN - 1] = dc; gi[KNN - 1] = ic;
#pragma unroll
          for (int k2 = KNN - 1; k2 > 0; --k2) {
            bool sw = (gd[k2] < gd[k2 - 1]) ||
                      (gd[k2] == gd[k2 - 1] && gi[k2] < gi[k2 - 1]);
            if (sw) {
              float td = gd[k2]; gd[k2] = gd[k2 - 1]; gd[k2 - 1] = td;
              int ti = gi[k2]; gi[k2] = gi[k2 - 1]; gi[k2 - 1] = ti;
            }
          }
        }
      }
    }
    u16* o = nn + (size_t)row * KNN;
    int jmax = (row == NBN - 1) ? (KNN - 1) : KNN;   // linspace tail drop
#pragma unroll
    for (int j = 0; j < KNN; ++j) o[j] = (u16)(gi[j] & (NPTS - 1));
    for (int j = 0; j < jmax; ++j)
      atomicAdd(&deg[b4096 + (gi[j] & (NPTS - 1))], 1);
  }
}

// k_out: 64 nodes/block x 4 threads/node (12 out-channels each), with the
// same XCD swizzle for gather locality. Proven arithmetic.
#define ONB 64
#define LPAD 52
__global__ __launch_bounds__(256)
void k_out_f(const float* __restrict__ xraw, const u16* __restrict__ nn,
             const int* __restrict__ deg,
             const float* __restrict__ W0, const float* __restrict__ W1,
             const float* __restrict__ bias, float* __restrict__ out) {
  __shared__ float w0[CH * CH], w1[CH * CH], bs[CH];
  __shared__ __align__(16) float fS[ONB * LPAD];
  __shared__ __align__(16) float txS[ONB * LPAD];
  __shared__ float dinvS[ONB];
  int tid = threadIdx.x;
  int bi = blockIdx.x;
  int n0 = (bi & 7) * NPTS + (bi >> 3) * ONB;   // XCD swizzle (perf-only)
  int b12 = n0 & ~(NPTS - 1);
  for (int i = tid; i < CH * CH; i += 256) { w0[i] = W0[i]; w1[i] = W1[i]; }
  if (tid < CH) bs[tid] = bias[tid];
  for (int i = tid; i < ONB * 12; i += 256) {
    int ln = i / 12, f4 = i % 12;
    *(float4*)(fS + ln * LPAD + f4 * 4) =
        *(const float4*)(xraw + (size_t)(n0 + ln) * CH + f4 * 4);
  }
  if (tid < ONB) {
    int dg = deg[n0 + tid];
    dinvS[tid] = (dg > 0) ? (1.0f / sqrtf((float)dg)) : 0.0f;
  }
  __syncthreads();

  int ln = tid >> 2, p = tid & 3;
  int node = n0 + ln;
  float dn = dinvS[ln];
  const u16* nrow = nn + (size_t)node * KNN;
  bool full = (node != NBN - 1);
  float tx[12];
#pragma unroll
  for (int i = 0; i < 12; ++i) tx[i] = 0.f;
#pragma unroll
  for (int j = 0; j < KNN; ++j) {
    if (j < KNN - 1 || full) {
      int s = nrow[j] & (NPTS - 1);
      int dgs = deg[b12 + s];
      float ds = (dgs > 0) ? (1.0f / sqrtf((float)dgs)) : 0.0f;
      float w = -(ds * dn);
      const float4* pr = (const float4*)(xraw + (size_t)(b12 + s) * CH + p * 12);
#pragma unroll
      for (int q3 = 0; q3 < 3; ++q3) {
        float4 v = pr[q3];
        tx[q3*4]   += w * v.x; tx[q3*4+1] += w * v.y;
        tx[q3*4+2] += w * v.z; tx[q3*4+3] += w * v.w;
      }
    }
  }
#pragma unroll
  for (int q3 = 0; q3 < 3; ++q3)
    *(float4*)(txS + ln * LPAD + p * 12 + q3 * 4) =
        make_float4(tx[q3*4], tx[q3*4+1], tx[q3*4+2], tx[q3*4+3]);
  __syncthreads();

  float acc[12];
#pragma unroll
  for (int i = 0; i < 12; ++i) acc[i] = bs[p * 12 + i];
  const float* fr = fS + ln * LPAD;
  const float* tr = txS + ln * LPAD;
#pragma unroll
  for (int c = 0; c < CH; ++c) {
    float fc = fr[c];
    const float* wr = w0 + c * CH + p * 12;
#pragma unroll
    for (int i = 0; i < 12; ++i) acc[i] += fc * wr[i];
  }
#pragma unroll
  for (int c = 0; c < CH; ++c) {
    float tc = tr[c];
    const float* wr = w1 + c * CH + p * 12;
#pragma unroll
    for (int i = 0; i < 12; ++i) acc[i] += tc * wr[i];
  }
  float* op = out + (size_t)node * CH + p * 12;
#pragma unroll
  for (int q3 = 0; q3 < 3; ++q3)
    *(float4*)(op + q3 * 4) =
        make_float4(acc[q3*4], acc[q3*4+1], acc[q3*4+2], acc[q3*4+3]);
}

// ======================= FALLBACK (round-4, proven) =======================
__global__ __launch_bounds__(256)
void k_zero(int* __restrict__ deg) { deg[blockIdx.x * 256 + threadIdx.x] = 0; }

__global__ __launch_bounds__(256)
void k_hist(const u16* __restrict__ nn, int* __restrict__ deg) {
  int node = blockIdx.x * 256 + threadIdx.x;
  int b12 = node & ~(NPTS - 1);
  int jmax = (node == NBN - 1) ? (KNN - 1) : KNN;
  for (int j = 0; j < jmax; ++j)
    atomicAdd(&deg[b12 + (nn[(size_t)node * KNN + j] & (NPTS - 1))], 1);
}

__global__ __launch_bounds__(256)
void k_dinv(const int* __restrict__ deg, float* __restrict__ dinv) {
  int i = blockIdx.x * 256 + threadIdx.x;
  int dg = deg[i];
  dinv[i] = (dg > 0) ? (1.0f / sqrtf((float)dg)) : 0.0f;
}

#define NQ    4
#define QCOLS (NPTS/NQ)
#define TCOLS 32
#define NTILES (QCOLS/TCOLS)
#define RPB   64

__global__ __launch_bounds__(256)
void k_knn_nb(const float* __restrict__ x, u16* __restrict__ nn) {
  __shared__ __align__(16) float tile[NQ * TCOLS * CH];
  __shared__ float nrmS[NQ * TCOLS];
  __shared__ float csq[NQ * TCOLS];
  int tid = threadIdx.x;
  int r0 = blockIdx.x * RPB;
  int b  = r0 >> 12;
  int q  = tid >> 6;
  int lr = tid & 63;
  int n  = (r0 + lr) & (NPTS - 1);
  const float* xb = x + (size_t)b * CH * NPTS;
  float rf[CH];
#pragma unroll
  for (int c = 0; c < CH; ++c) rf[c] = xb[(size_t)c * NPTS + n];
  float sqn;
  {
    float a0 = 0, a1 = 0, a2 = 0, a3 = 0;
#pragma unroll
    for (int k = 0; k < CH; k += 4) {
      a0 += rf[k] * rf[k]; a1 += rf[k+1] * rf[k+1];
      a2 += rf[k+2] * rf[k+2]; a3 += rf[k+3] * rf[k+3];
    }
    float nrm = fmaxf(sqrtf((a0 + a1) + (a2 + a3)), 1e-12f);
#pragma unroll
    for (int c = 0; c < CH; ++c) rf[c] = rf[c] / nrm;
    a0 = a1 = a2 = a3 = 0;
#pragma unroll
    for (int k = 0; k < CH; k += 4) {
      a0 += rf[k] * rf[k]; a1 += rf[k+1] * rf[k+1];
      a2 += rf[k+2] * rf[k+2]; a3 += rf[k+3] * rf[k+3];
    }
    sqn = (a0 + a1) + (a2 + a3);
  }
  float d[KNN]; int id[KNN];
#pragma unroll
  for (int j = 0; j < KNN; ++j) { d[j] = 3.4e38f; id[j] = 0x7fffffff; }
  for (int t = 0; t < NTILES; ++t) {
    __syncthreads();
#pragma unroll
    for (int qq = 0; qq < NQ; ++qq) {
      int colbase = qq * QCOLS + t * TCOLS;
      float* dst = tile + qq * TCOLS * CH;
#pragma unroll
      for (int it = 0; it < 6; ++it) {
        int i = it * 256 + tid;
        int c = i >> 5, p = i & 31;
        dst[p * CH + c] = xb[(size_t)c * NPTS + colbase + p];
      }
    }
    __syncthreads();
    if (tid < NQ * TCOLS) {
      const float* cp = tile + tid * CH;
      float a0 = 0, a1 = 0, a2 = 0, a3 = 0;
#pragma unroll
      for (int k = 0; k < CH; k += 4) {
        float4 v = *(const float4*)(cp + k);
        a0 += v.x * v.x; a1 += v.y * v.y; a2 += v.z * v.z; a3 += v.w * v.w;
      }
      nrmS[tid] = fmaxf(sqrtf((a0 + a1) + (a2 + a3)), 1e-12f);
    }
    __syncthreads();
    for (int i = tid; i < NQ * TCOLS * CH; i += 256)
      tile[i] = tile[i] / nrmS[i / CH];
    __syncthreads();
    if (tid < NQ * TCOLS) {
      const float* cp = tile + tid * CH;
      float a0 = 0, a1 = 0, a2 = 0, a3 = 0;
#pragma unroll
      for (int k = 0; k < CH; k += 4) {
        float4 v = *(const float4*)(cp + k);
        a0 += v.x * v.x; a1 += v.y * v.y; a2 += v.z * v.z; a3 += v.w * v.w;
      }
      csq[tid] = (a0 + a1) + (a2 + a3);
    }
    __syncthreads();
    int cbase = q * QCOLS + t * TCOLS;
    const float* tq = tile + q * TCOLS * CH;
    for (int cc = 0; cc < TCOLS; ++cc) {
      const float* cp = tq + cc * CH;
      float a0 = 0, a1 = 0, a2 = 0, a3 = 0;
#pragma unroll
      for (int k = 0; k < CH; k += 4) {
        float4 v = *(const float4*)(cp + k);
        a0 += rf[k] * v.x; a1 += rf[k+1] * v.y;
        a2 += rf[k+2] * v.z; a3 += rf[k+3] * v.w;
      }
      float dist = (sqn + csq[q * TCOLS + cc]) - 2.0f * ((a0 + a1) + (a2 + a3));
      if (dist < d[KNN - 1]) {
        d[KNN - 1] = dist; id[KNN - 1] = cbase + cc;
#pragma unroll
        for (int k2 = KNN - 1; k2 > 0; --k2) {
          if (d[k2] < d[k2 - 1]) {
            float td = d[k2]; d[k2] = d[k2 - 1]; d[k2 - 1] = td;
            int ti = id[k2]; id[k2] = id[k2 - 1]; id[k2 - 1] = ti;
          }
        }
      }
    }
  }
  __syncthreads();
  float* md = tile;
  int*   mi = (int*)(tile + 256 * KNN);
#pragma unroll
  for (int j = 0; j < KNN; ++j) { md[tid * KNN + j] = d[j]; mi[tid * KNN + j] = id[j]; }
  __syncthreads();
  if (tid < RPB) {
    float fd[KNN]; int fi[KNN];
#pragma unroll
    for (int j = 0; j < KNN; ++j) { fd[j] = 3.4e38f; fi[j] = 0x7fffffff; }
    for (int qq = 0; qq < NQ; ++qq) {
      int s = qq * RPB + tid;
      for (int j = 0; j < KNN; ++j) {
        float dc = md[s * KNN + j]; int ic = mi[s * KNN + j];
        if (dc < fd[KNN - 1]) {
          fd[KNN - 1] = dc; fi[KNN - 1] = ic;
#pragma unroll
          for (int k2 = KNN - 1; k2 > 0; --k2) {
            if (fd[k2] < fd[k2 - 1]) {
              float td = fd[k2]; fd[k2] = fd[k2 - 1]; fd[k2 - 1] = td;
              int ti = fi[k2]; fi[k2] = fi[k2 - 1]; fi[k2 - 1] = ti;
            }
          }
        }
      }
    }
    u16* o = nn + (size_t)(r0 + tid) * KNN;
#pragma unroll
    for (int j = 0; j < KNN; ++j) o[j] = (u16)(fi[j] & (NPTS - 1));
  }
}

__global__ __launch_bounds__(256)
void k_out_nb(const float* __restrict__ x, const u16* __restrict__ nn,
              const float* __restrict__ dinv,
              const float* __restrict__ W0, const float* __restrict__ W1,
              const float* __restrict__ bias, float* __restrict__ out) {
  __shared__ float w0[CH * CH], w1[CH * CH], bs[CH];
  for (int i = threadIdx.x; i < CH * CH; i += 256) { w0[i] = W0[i]; w1[i] = W1[i]; }
  if (threadIdx.x < CH) bs[threadIdx.x] = bias[threadIdx.x];
  __syncthreads();
  int node = blockIdx.x * 256 + threadIdx.x;
  int b = node >> 12, n = node & (NPTS - 1);
  const float* xb = x + (size_t)b * CH * NPTS;
  float f[CH], acc[CH], tx[CH];
#pragma unroll
  for (int c = 0; c < CH; ++c) f[c] = xb[(size_t)c * NPTS + n];
#pragma unroll
  for (int o = 0; o < CH; ++o) acc[o] = bs[o];
#pragma unroll
  for (int c = 0; c < CH; ++c) {
    float fc = f[c];
    const float* wr = w0 + c * CH;
#pragma unroll
    for (int o = 0; o < CH; ++o) acc[o] += fc * wr[o];
  }
#pragma unroll
  for (int c = 0; c < CH; ++c) tx[c] = 0.f;
  float dn = dinv[node];
  int jmax = (node == NBN - 1) ? (KNN - 1) : KNN;
  for (int j = 0; j < jmax; ++j) {
    int s = nn[(size_t)node * KNN + j] & (NPTS - 1);
    float w = -(dinv[(b << 12) + s] * dn);
#pragma unroll
    for (int c = 0; c < CH; ++c) tx[c] += w * xb[(size_t)c * NPTS + s];
  }
#pragma unroll
  for (int c = 0; c < CH; ++c) {
    float tc = tx[c];
    const float* wr = w1 + c * CH;
#pragma unroll
    for (int o = 0; o < CH; ++o) acc[o] += tc * wr[o];
  }
  float4* op = (float4*)(out + (size_t)node * CH);
#pragma unroll
  for (int i = 0; i < CH / 4; ++i)
    op[i] = make_float4(acc[4*i], acc[4*i+1], acc[4*i+2], acc[4*i+3]);
}

extern "C" void kernel_launch(void* const* d_in, const int* in_sizes, int n_in,
                              void* d_out, int out_size, void* d_ws, size_t ws_size,
                              hipStream_t stream) {
  const float* x    = (const float*)d_in[0];
  const float* W0   = (const float*)d_in[1];
  const float* W1   = (const float*)d_in[2];
  const float* bias = (const float*)d_in[3];
  float* out = (float*)d_out;
  char* w = (char*)d_ws;

  const size_t SZ_XN   = (size_t)NBN * CH * 4;            //  6,291,456
  const size_t SZ_XRAW = (size_t)NBN * CH * 4;            //  6,291,456
  const size_t SZ_CSQ  = (size_t)NBN * 4;                 //    131,072
  const size_t SZ_NN   = (size_t)NBN * KNN * 2;           //    589,824
  const size_t SZ_DEG  = (size_t)NBN * 4;                 //    131,072
  const size_t SZ_AB   = (size_t)NBN * 128 * 2;           //  8,388,608
  const size_t SZ_CI   = (size_t)NBN * 16 * NCAND * 4;    // 25,165,824
  const size_t needF = SZ_XN + SZ_XRAW + SZ_CSQ + SZ_NN + SZ_DEG
                     + 2 * SZ_AB + SZ_CI;                 // ~55.4 MB

  if (ws_size >= needF) {          // FAST path: MFMA filter + fp32 rescore
    size_t off = 0;
    float* xn   = (float*)(w + off); off += SZ_XN;
    float* xraw = (float*)(w + off); off += SZ_XRAW;
    float* csq  = (float*)(w + off); off += SZ_CSQ;
    u16*   nn   = (u16*)  (w + off); off += SZ_NN;
    int*   deg  = (int*)  (w + off); off += SZ_DEG;
    u16*   Abuf = (u16*)  (w + off); off += SZ_AB;
    u16*   Bbuf = (u16*)  (w + off); off += SZ_AB;
    int*   candi= (int*)  (w + off);
    k_prep    <<<NBN / 256, 256, 0, stream>>>(x, xraw, xn, csq, Abuf, Bbuf, deg);
    k_knn_m   <<<dim3(NBN / 64, 4), 256, 0, stream>>>(Abuf, Bbuf, candi);
    k_rescore <<<NBN / RR, 256, 0, stream>>>(xn, csq, candi, nn, deg);
    k_out_f   <<<NBN / ONB, 256, 0, stream>>>(xraw, nn, deg, W0, W1, bias, out);
  } else {                         // FALLBACK: proven round-4 path (852 KB)
    u16*   nn   = (u16*)w;
    int*   deg  = (int*)(w + SZ_NN);
    float* dinv = (float*)(w + SZ_NN + SZ_DEG);
    k_knn_nb <<<NBN / RPB, 256, 0, stream>>>(x, nn);
    k_zero   <<<NBN / 256, 256, 0, stream>>>(deg);
    k_hist   <<<NBN / 256, 256, 0, stream>>>(nn, deg);
    k_dinv   <<<NBN / 256, 256, 0, stream>>>(deg, dinv);
    k_out_nb <<<NBN / 256, 256, 0, stream>>>(x, nn, dinv, W0, W1, bias, out);
  }
}

// Round 15
// 283.576 us; speedup vs baseline: 2.1064x; 2.1064x over previous
//
#include <hip/hip_runtime.h>

#define BATCH 8
#define CH    48
#define NPTS  4096
#define NBN   (BATCH*NPTS)
#define KNN   9
#define NCAND 12             // per-lane filter depth

typedef unsigned short u16;
typedef unsigned int   u32;
typedef unsigned long long u64;
typedef __bf16 bf16x8 __attribute__((ext_vector_type(8)));
typedef float  f32x4  __attribute__((ext_vector_type(4)));

__device__ __forceinline__ float bf2f(u16 v) { return __uint_as_float(((u32)v) << 16); }
__device__ __forceinline__ u16 f2bf(float f) {
  u32 u = __float_as_uint(f);
  u = (u + 0x7fffu + ((u >> 16) & 1u)) >> 16;
  return (u16)u;
}

// ======================= FAST PATH (ws >= ~83 MB) =======================
// k_prep: normalize per reference; write xraw/xn fp32 node-major, csq;
// build hi/lo-split bf16 operands. A layout MFMA-coalesced:
// [tile16][variant(4)][lane(64)][8 bf16]; B [node][128]. Zero deg.
__global__ __launch_bounds__(256)
void k_prep(const float* __restrict__ x, float* __restrict__ xraw,
            float* __restrict__ xn, float* __restrict__ csq,
            u16* __restrict__ Abuf, u16* __restrict__ Bbuf,
            int* __restrict__ deg) {
  int node = blockIdx.x * 256 + threadIdx.x;
  deg[node] = 0;
  int b = node >> 12, n = node & (NPTS - 1);
  const float* xb = x + (size_t)b * CH * NPTS;
  float f[CH];
#pragma unroll
  for (int c = 0; c < CH; ++c) f[c] = xb[(size_t)c * NPTS + n];
  float a0 = 0, a1 = 0, a2 = 0, a3 = 0;
#pragma unroll
  for (int k = 0; k < CH; k += 4) {
    a0 += f[k] * f[k]; a1 += f[k+1] * f[k+1];
    a2 += f[k+2] * f[k+2]; a3 += f[k+3] * f[k+3];
  }
  float nrm = fmaxf(sqrtf((a0 + a1) + (a2 + a3)), 1e-12f);
  float xv[CH];
#pragma unroll
  for (int c = 0; c < CH; ++c) xv[c] = f[c] / nrm;     // true division (ref)
  a0 = a1 = a2 = a3 = 0;
#pragma unroll
  for (int k = 0; k < CH; k += 4) {
    a0 += xv[k] * xv[k]; a1 += xv[k+1] * xv[k+1];
    a2 += xv[k+2] * xv[k+2]; a3 += xv[k+3] * xv[k+3];
  }
  float csqv = (a0 + a1) + (a2 + a3);
  csq[node] = csqv;
  float4* ro = (float4*)(xraw + (size_t)node * CH);
  float4* no = (float4*)(xn   + (size_t)node * CH);
#pragma unroll
  for (int i = 0; i < CH / 4; ++i) {
    ro[i] = make_float4(f[4*i], f[4*i+1], f[4*i+2], f[4*i+3]);
    no[i] = make_float4(xv[4*i], xv[4*i+1], xv[4*i+2], xv[4*i+3]);
  }
  u16 ah[64], al[64];
#pragma unroll
  for (int k = 0; k < CH; ++k) {
    float av = -2.0f * xv[k];
    u16 h = f2bf(av); ah[k] = h; al[k] = f2bf(av - bf2f(h));
  }
  { u16 h = f2bf(csqv); ah[48] = h; al[48] = f2bf(csqv - bf2f(h)); }
#pragma unroll
  for (int k = 49; k < 64; ++k) { ah[k] = 0; al[k] = 0; }
  u16* Bh = Bbuf + (size_t)node * 128;
#pragma unroll
  for (int k = 0; k < CH; ++k) {
    float bv = xv[k];
    u16 h = f2bf(bv); Bh[k] = h; Bh[64 + k] = f2bf(bv - bf2f(h));
  }
  Bh[48] = 0x3F80; Bh[64 + 48] = 0;            // 1.0 bf16 exact
#pragma unroll
  for (int k = 49; k < 64; ++k) { Bh[k] = 0; Bh[64 + k] = 0; }
  u16* Ag = Abuf + (size_t)(node >> 4) * 2048 + (size_t)(node & 15) * 8;
#pragma unroll
  for (int v = 0; v < 4; ++v) {
    const u16* src = (v < 2) ? ah : al;
    int koff = (v & 1) * 32;
#pragma unroll
    for (int q = 0; q < 4; ++q) {
      uint4 pk;
      const u16* s = src + koff + q * 8;
      pk.x = (u32)s[0] | ((u32)s[1] << 16);
      pk.y = (u32)s[2] | ((u32)s[3] << 16);
      pk.z = (u32)s[4] | ((u32)s[5] << 16);
      pk.w = (u32)s[6] | ((u32)s[7] << 16);
      *(uint4*)(Ag + v * 512 + q * 128) = pk;
    }
  }
}

// k_knn_m: wave = 16-row panel; blockIdx.y = column quarter (64 tiles of 16).
// 6 MFMAs/tile (hh,hl,lh). Branchless packed-u32 top-12 in named registers.
// Epilogue emits u64 = (packed_key << 12) | global_col  (total order, no ties).
#define STEP(si) { u32 _lo = min(si, x); x = max(si, x); si = _lo; }
__global__ __launch_bounds__(256, 8)
void k_knn_m(const u16* __restrict__ Abuf, const u16* __restrict__ Bbuf,
             u64* __restrict__ candu) {
  int tid = threadIdx.x;
  int lane = tid & 63;
  int quad = lane >> 4, m16 = lane & 15;
  int panel = blockIdx.x * 4 + (tid >> 6);
  int row = panel * 16 + m16;
  int b4096 = row & ~(NPTS - 1);
  int quarter = blockIdx.y;
  int ct0 = quarter * 64;

  const __bf16* Bb = (const __bf16*)Bbuf + (size_t)row * 128;
  bf16x8 bh0 = *(const bf16x8*)(Bb + quad * 8);
  bf16x8 bh1 = *(const bf16x8*)(Bb + 32 + quad * 8);
  bf16x8 bl0 = *(const bf16x8*)(Bb + 64 + quad * 8);
  bf16x8 bl1 = *(const bf16x8*)(Bb + 96 + quad * 8);

  const __bf16* Ag = (const __bf16*)Abuf + (size_t)(b4096 >> 4) * 2048
                     + (size_t)lane * 8;

  u32 s0=~0u,s1=~0u,s2=~0u,s3=~0u,s4=~0u,s5=~0u,
      s6=~0u,s7=~0u,s8=~0u,s9=~0u,s10=~0u,s11=~0u;

  for (int t = 0; t < 64; ++t) {
    int ct = ct0 + t;
    const __bf16* ap = Ag + (size_t)ct * 2048;
    bf16x8 a0 = *(const bf16x8*)(ap);
    bf16x8 a1 = *(const bf16x8*)(ap + 512);
    bf16x8 a2 = *(const bf16x8*)(ap + 1024);
    bf16x8 a3 = *(const bf16x8*)(ap + 1536);
    f32x4 acc = {0.f, 0.f, 0.f, 0.f};
    acc = __builtin_amdgcn_mfma_f32_16x16x32_bf16(a0, bh0, acc, 0, 0, 0);
    acc = __builtin_amdgcn_mfma_f32_16x16x32_bf16(a1, bh1, acc, 0, 0, 0);
    acc = __builtin_amdgcn_mfma_f32_16x16x32_bf16(a0, bl0, acc, 0, 0, 0);
    acc = __builtin_amdgcn_mfma_f32_16x16x32_bf16(a1, bl1, acc, 0, 0, 0);
    acc = __builtin_amdgcn_mfma_f32_16x16x32_bf16(a2, bh0, acc, 0, 0, 0);
    acc = __builtin_amdgcn_mfma_f32_16x16x32_bf16(a3, bh1, acc, 0, 0, 0);
#pragma unroll
    for (int r = 0; r < 4; ++r) {
      u32 u = __float_as_uint(acc[r]);
      u ^= (u32)((int)u >> 31) | 0x80000000u;        // order-preserving map
      u32 x = (u & 0xFFFFFC00u) | (u32)((ct << 2) | r);
      STEP(s0) STEP(s1) STEP(s2) STEP(s3) STEP(s4) STEP(s5)
      STEP(s6) STEP(s7) STEP(s8) STEP(s9) STEP(s10) STEP(s11)
    }
  }

  u64* o = candu + (((size_t)row * 4 + quarter) * 4 + quad) * NCAND;
#define EMIT(j, sv) { u32 col = ((sv & 0x3FFu) >> 2) * 16 + quad * 4 + (sv & 3u); \
                      o[j] = ((u64)sv << 12) | (u64)col; }
  EMIT(0, s0)  EMIT(1, s1)  EMIT(2, s2)  EMIT(3, s3)
  EMIT(4, s4)  EMIT(5, s5)  EMIT(6, s6)  EMIT(7, s7)
  EMIT(8, s8)  EMIT(9, s9)  EMIT(10, s10) EMIT(11, s11)
#undef EMIT
}

// k_reduce: per row, top-12 of the 192 u64 candidates (coalesced reads, no
// feature gathers). 64 rows/block x 4 threads/row; branchless u64 STEP
// network in named registers; 2-stage (48 each -> 48 merged by thread 0).
#define STEP64(si) { u64 _lo = (x < si) ? x : si; u64 _hi = (x < si) ? si : x; \
                     si = _lo; x = _hi; }
__global__ __launch_bounds__(256, 4)
void k_reduce(const u64* __restrict__ candu, u32* __restrict__ cand12) {
  __shared__ u64 ls[64 * 4 * NCAND];   // 24,576 B
  int tid = threadIdx.x;
  int lr = tid >> 2, q = tid & 3;
  int row = blockIdx.x * 64 + lr;
  const u64* src = candu + (size_t)row * 192 + q * 48;
  u64 t0=~0ull,t1=~0ull,t2=~0ull,t3=~0ull,t4=~0ull,t5=~0ull,
      t6=~0ull,t7=~0ull,t8=~0ull,t9=~0ull,t10=~0ull,t11=~0ull;
  for (int s = 0; s < 48; ++s) {
    u64 x = src[s];
    STEP64(t0) STEP64(t1) STEP64(t2) STEP64(t3) STEP64(t4) STEP64(t5)
    STEP64(t6) STEP64(t7) STEP64(t8) STEP64(t9) STEP64(t10) STEP64(t11)
  }
  u64* lw = ls + (size_t)(lr * 4 + q) * NCAND;
  lw[0]=t0; lw[1]=t1; lw[2]=t2; lw[3]=t3; lw[4]=t4; lw[5]=t5;
  lw[6]=t6; lw[7]=t7; lw[8]=t8; lw[9]=t9; lw[10]=t10; lw[11]=t11;
  __syncthreads();
  if (q == 0) {
    u64 g0=~0ull,g1=~0ull,g2=~0ull,g3=~0ull,g4=~0ull,g5=~0ull,
        g6=~0ull,g7=~0ull,g8=~0ull,g9=~0ull,g10=~0ull,g11=~0ull;
    const u64* lsrc = ls + (size_t)lr * 48;
    for (int s = 0; s < 48; ++s) {
      u64 x = lsrc[s];
      STEP64(g0) STEP64(g1) STEP64(g2) STEP64(g3) STEP64(g4) STEP64(g5)
      STEP64(g6) STEP64(g7) STEP64(g8) STEP64(g9) STEP64(g10) STEP64(g11)
    }
    u32* o = cand12 + (size_t)row * NCAND;
    o[0]=(u32)(g0&0xFFFu); o[1]=(u32)(g1&0xFFFu); o[2]=(u32)(g2&0xFFFu);
    o[3]=(u32)(g3&0xFFFu); o[4]=(u32)(g4&0xFFFu); o[5]=(u32)(g5&0xFFFu);
    o[6]=(u32)(g6&0xFFFu); o[7]=(u32)(g7&0xFFFu); o[8]=(u32)(g8&0xFFFu);
    o[9]=(u32)(g9&0xFFFu); o[10]=(u32)(g10&0xFFFu); o[11]=(u32)(g11&0xFFFu);
  }
}

// k_rescore: 16 rows/block x 16 threads/row; threads 0..11 each gather ONE
// candidate row and compute the exact fp32 dist (proven formula); thread 0
// merges 12 with the exact (dist, idx) comparator -> top-9. Fused nn write
// + degree histogram (tail edge drop). Only 12 gathers/row.
#define RR 16
__global__ __launch_bounds__(256, 4)
void k_rescore(const float* __restrict__ xn, const float* __restrict__ csq,
               const u32* __restrict__ cand12,
               u16* __restrict__ nn, int* __restrict__ deg) {
  __shared__ float dS[RR * NCAND];
  __shared__ int   iS[RR * NCAND];
  int tid = threadIdx.x;
  int lr = tid >> 4, q = tid & 15;
  int bi = blockIdx.x;
  int row = (bi & 7) * NPTS + (bi >> 3) * RR + lr;   // XCD swizzle (perf-only)
  int b4096 = row & ~(NPTS - 1);
  const float* xnb = xn + (size_t)b4096 * CH;
  if (q < NCAND) {
    float rf[CH];
    const float4* p = (const float4*)(xn + (size_t)row * CH);
#pragma unroll
    for (int i = 0; i < CH / 4; ++i) {
      float4 v = p[i];
      rf[4*i] = v.x; rf[4*i+1] = v.y; rf[4*i+2] = v.z; rf[4*i+3] = v.w;
    }
    float sqn = csq[row];
    int c = (int)(cand12[(size_t)row * NCAND + q] & (NPTS - 1));
    const float4* cp = (const float4*)(xnb + (size_t)c * CH);
    float a0 = 0, a1 = 0, a2 = 0, a3 = 0;
#pragma unroll
    for (int i = 0; i < CH / 4; ++i) {
      float4 v = cp[i];
      a0 += rf[4*i]   * v.x; a1 += rf[4*i+1] * v.y;
      a2 += rf[4*i+2] * v.z; a3 += rf[4*i+3] * v.w;
    }
    float dist = (sqn + csq[b4096 + c]) - 2.0f * ((a0 + a1) + (a2 + a3));
    dS[lr * NCAND + q] = dist;
    iS[lr * NCAND + q] = c;
  }
  __syncthreads();
  if (q == 0) {
    float gd[KNN]; int gi[KNN];
#pragma unroll
    for (int j = 0; j < KNN; ++j) { gd[j] = 3.4e38f; gi[j] = 0x7fffffff; }
    for (int s = 0; s < NCAND; ++s) {
      float dc = dS[lr * NCAND + s]; int ic = iS[lr * NCAND + s];
      if (dc < gd[KNN - 1] || (dc == gd[KNN - 1] && ic < gi[KNN - 1])) {
        gd[KNN - 1] = dc; gi[KNN - 1] = ic;
#pragma unroll
        for (int k2 = KNN - 1; k2 > 0; --k2) {
          bool sw = (gd[k2] < gd[k2 - 1]) ||
                    (gd[k2] == gd[k2 - 1] && gi[k2] < gi[k2 - 1]);
          if (sw) {
            float td = gd[k2]; gd[k2] = gd[k2 - 1]; gd[k2 - 1] = td;
            int ti = gi[k2]; gi[k2] = gi[k2 - 1]; gi[k2 - 1] = ti;
          }
        }
      }
    }
    u16* o = nn + (size_t)row * KNN;
    int jmax = (row == NBN - 1) ? (KNN - 1) : KNN;   // linspace tail drop
#pragma unroll
    for (int j = 0; j < KNN; ++j) o[j] = (u16)(gi[j] & (NPTS - 1));
    for (int j = 0; j < jmax; ++j)
      atomicAdd(&deg[b4096 + (gi[j] & (NPTS - 1))], 1);
  }
}

// k_out: 64 nodes/block x 4 threads/node (12 out-channels each), XCD swizzle.
#define ONB 64
#define LPAD 52
__global__ __launch_bounds__(256)
void k_out_f(const float* __restrict__ xraw, const u16* __restrict__ nn,
             const int* __restrict__ deg,
             const float* __restrict__ W0, const float* __restrict__ W1,
             const float* __restrict__ bias, float* __restrict__ out) {
  __shared__ float w0[CH * CH], w1[CH * CH], bs[CH];
  __shared__ __align__(16) float fS[ONB * LPAD];
  __shared__ __align__(16) float txS[ONB * LPAD];
  __shared__ float dinvS[ONB];
  int tid = threadIdx.x;
  int bi = blockIdx.x;
  int n0 = (bi & 7) * NPTS + (bi >> 3) * ONB;   // XCD swizzle (perf-only)
  int b12 = n0 & ~(NPTS - 1);
  for (int i = tid; i < CH * CH; i += 256) { w0[i] = W0[i]; w1[i] = W1[i]; }
  if (tid < CH) bs[tid] = bias[tid];
  for (int i = tid; i < ONB * 12; i += 256) {
    int ln = i / 12, f4 = i % 12;
    *(float4*)(fS + ln * LPAD + f4 * 4) =
        *(const float4*)(xraw + (size_t)(n0 + ln) * CH + f4 * 4);
  }
  if (tid < ONB) {
    int dg = deg[n0 + tid];
    dinvS[tid] = (dg > 0) ? (1.0f / sqrtf((float)dg)) : 0.0f;
  }
  __syncthreads();

  int ln = tid >> 2, p = tid & 3;
  int node = n0 + ln;
  float dn = dinvS[ln];
  const u16* nrow = nn + (size_t)node * KNN;
  bool full = (node != NBN - 1);
  float tx[12];
#pragma unroll
  for (int i = 0; i < 12; ++i) tx[i] = 0.f;
#pragma unroll
  for (int j = 0; j < KNN; ++j) {
    if (j < KNN - 1 || full) {
      int s = nrow[j] & (NPTS - 1);
      int dgs = deg[b12 + s];
      float ds = (dgs > 0) ? (1.0f / sqrtf((float)dgs)) : 0.0f;
      float w = -(ds * dn);
      const float4* pr = (const float4*)(xraw + (size_t)(b12 + s) * CH + p * 12);
#pragma unroll
      for (int q3 = 0; q3 < 3; ++q3) {
        float4 v = pr[q3];
        tx[q3*4]   += w * v.x; tx[q3*4+1] += w * v.y;
        tx[q3*4+2] += w * v.z; tx[q3*4+3] += w * v.w;
      }
    }
  }
#pragma unroll
  for (int q3 = 0; q3 < 3; ++q3)
    *(float4*)(txS + ln * LPAD + p * 12 + q3 * 4) =
        make_float4(tx[q3*4], tx[q3*4+1], tx[q3*4+2], tx[q3*4+3]);
  __syncthreads();

  float acc[12];
#pragma unroll
  for (int i = 0; i < 12; ++i) acc[i] = bs[p * 12 + i];
  const float* fr = fS + ln * LPAD;
  const float* tr = txS + ln * LPAD;
#pragma unroll
  for (int c = 0; c < CH; ++c) {
    float fc = fr[c];
    const float* wr = w0 + c * CH + p * 12;
#pragma unroll
    for (int i = 0; i < 12; ++i) acc[i] += fc * wr[i];
  }
#pragma unroll
  for (int c = 0; c < CH; ++c) {
    float tc = tr[c];
    const float* wr = w1 + c * CH + p * 12;
#pragma unroll
    for (int i = 0; i < 12; ++i) acc[i] += tc * wr[i];
  }
  float* op = out + (size_t)node * CH + p * 12;
#pragma unroll
  for (int q3 = 0; q3 < 3; ++q3)
    *(float4*)(op + q3 * 4) =
        make_float4(acc[q3*4], acc[q3*4+1], acc[q3*4+2], acc[q3*4+3]);
}

// ======================= FALLBACK (round-4, proven) =======================
__global__ __launch_bounds__(256)
void k_zero(int* __restrict__ deg) { deg[blockIdx.x * 256 + threadIdx.x] = 0; }

__global__ __launch_bounds__(256)
void k_hist(const u16* __restrict__ nn, int* __restrict__ deg) {
  int node = blockIdx.x * 256 + threadIdx.x;
  int b12 = node & ~(NPTS - 1);
  int jmax = (node == NBN - 1) ? (KNN - 1) : KNN;
  for (int j = 0; j < jmax; ++j)
    atomicAdd(&deg[b12 + (nn[(size_t)node * KNN + j] & (NPTS - 1))], 1);
}

__global__ __launch_bounds__(256)
void k_dinv(const int* __restrict__ deg, float* __restrict__ dinv) {
  int i = blockIdx.x * 256 + threadIdx.x;
  int dg = deg[i];
  dinv[i] = (dg > 0) ? (1.0f / sqrtf((float)dg)) : 0.0f;
}

#define NQ    4
#define QCOLS (NPTS/NQ)
#define TCOLS 32
#define NTILES (QCOLS/TCOLS)
#define RPB   64

__global__ __launch_bounds__(256)
void k_knn_nb(const float* __restrict__ x, u16* __restrict__ nn) {
  __shared__ __align__(16) float tile[NQ * TCOLS * CH];
  __shared__ float nrmS[NQ * TCOLS];
  __shared__ float csq[NQ * TCOLS];
  int tid = threadIdx.x;
  int r0 = blockIdx.x * RPB;
  int b  = r0 >> 12;
  int q  = tid >> 6;
  int lr = tid & 63;
  int n  = (r0 + lr) & (NPTS - 1);
  const float* xb = x + (size_t)b * CH * NPTS;
  float rf[CH];
#pragma unroll
  for (int c = 0; c < CH; ++c) rf[c] = xb[(size_t)c * NPTS + n];
  float sqn;
  {
    float a0 = 0, a1 = 0, a2 = 0, a3 = 0;
#pragma unroll
    for (int k = 0; k < CH; k += 4) {
      a0 += rf[k] * rf[k]; a1 += rf[k+1] * rf[k+1];
      a2 += rf[k+2] * rf[k+2]; a3 += rf[k+3] * rf[k+3];
    }
    float nrm = fmaxf(sqrtf((a0 + a1) + (a2 + a3)), 1e-12f);
#pragma unroll
    for (int c = 0; c < CH; ++c) rf[c] = rf[c] / nrm;
    a0 = a1 = a2 = a3 = 0;
#pragma unroll
    for (int k = 0; k < CH; k += 4) {
      a0 += rf[k] * rf[k]; a1 += rf[k+1] * rf[k+1];
      a2 += rf[k+2] * rf[k+2]; a3 += rf[k+3] * rf[k+3];
    }
    sqn = (a0 + a1) + (a2 + a3);
  }
  float d[KNN]; int id[KNN];
#pragma unroll
  for (int j = 0; j < KNN; ++j) { d[j] = 3.4e38f; id[j] = 0x7fffffff; }
  for (int t = 0; t < NTILES; ++t) {
    __syncthreads();
#pragma unroll
    for (int qq = 0; qq < NQ; ++qq) {
      int colbase = qq * QCOLS + t * TCOLS;
      float* dst = tile + qq * TCOLS * CH;
#pragma unroll
      for (int it = 0; it < 6; ++it) {
        int i = it * 256 + tid;
        int c = i >> 5, p = i & 31;
        dst[p * CH + c] = xb[(size_t)c * NPTS + colbase + p];
      }
    }
    __syncthreads();
    if (tid < NQ * TCOLS) {
      const float* cp = tile + tid * CH;
      float a0 = 0, a1 = 0, a2 = 0, a3 = 0;
#pragma unroll
      for (int k = 0; k < CH; k += 4) {
        float4 v = *(const float4*)(cp + k);
        a0 += v.x * v.x; a1 += v.y * v.y; a2 += v.z * v.z; a3 += v.w * v.w;
      }
      nrmS[tid] = fmaxf(sqrtf((a0 + a1) + (a2 + a3)), 1e-12f);
    }
    __syncthreads();
    for (int i = tid; i < NQ * TCOLS * CH; i += 256)
      tile[i] = tile[i] / nrmS[i / CH];
    __syncthreads();
    if (tid < NQ * TCOLS) {
      const float* cp = tile + tid * CH;
      float a0 = 0, a1 = 0, a2 = 0, a3 = 0;
#pragma unroll
      for (int k = 0; k < CH; k += 4) {
        float4 v = *(const float4*)(cp + k);
        a0 += v.x * v.x; a1 += v.y * v.y; a2 += v.z * v.z; a3 += v.w * v.w;
      }
      csq[tid] = (a0 + a1) + (a2 + a3);
    }
    __syncthreads();
    int cbase = q * QCOLS + t * TCOLS;
    const float* tq = tile + q * TCOLS * CH;
    for (int cc = 0; cc < TCOLS; ++cc) {
      const float* cp = tq + cc * CH;
      float a0 = 0, a1 = 0, a2 = 0, a3 = 0;
#pragma unroll
      for (int k = 0; k < CH; k += 4) {
        float4 v = *(const float4*)(cp + k);
        a0 += rf[k] * v.x; a1 += rf[k+1] * v.y;
        a2 += rf[k+2] * v.z; a3 += rf[k+3] * v.w;
      }
      float dist = (sqn + csq[q * TCOLS + cc]) - 2.0f * ((a0 + a1) + (a2 + a3));
      if (dist < d[KNN - 1]) {
        d[KNN - 1] = dist; id[KNN - 1] = cbase + cc;
#pragma unroll
        for (int k2 = KNN - 1; k2 > 0; --k2) {
          if (d[k2] < d[k2 - 1]) {
            float td = d[k2]; d[k2] = d[k2 - 1]; d[k2 - 1] = td;
            int ti = id[k2]; id[k2] = id[k2 - 1]; id[k2 - 1] = ti;
          }
        }
      }
    }
  }
  __syncthreads();
  float* md = tile;
  int*   mi = (int*)(tile + 256 * KNN);
#pragma unroll
  for (int j = 0; j < KNN; ++j) { md[tid * KNN + j] = d[j]; mi[tid * KNN + j] = id[j]; }
  __syncthreads();
  if (tid < RPB) {
    float fd[KNN]; int fi[KNN];
#pragma unroll
    for (int j = 0; j < KNN; ++j) { fd[j] = 3.4e38f; fi[j] = 0x7fffffff; }
    for (int qq = 0; qq < NQ; ++qq) {
      int s = qq * RPB + tid;
      for (int j = 0; j < KNN; ++j) {
        float dc = md[s * KNN + j]; int ic = mi[s * KNN + j];
        if (dc < fd[KNN - 1]) {
          fd[KNN - 1] = dc; fi[KNN - 1] = ic;
#pragma unroll
          for (int k2 = KNN - 1; k2 > 0; --k2) {
            if (fd[k2] < fd[k2 - 1]) {
              float td = fd[k2]; fd[k2] = fd[k2 - 1]; fd[k2 - 1] = td;
              int ti = fi[k2]; fi[k2] = fi[k2 - 1]; fi[k2 - 1] = ti;
            }
          }
        }
      }
    }
    u16* o = nn + (size_t)(r0 + tid) * KNN;
#pragma unroll
    for (int j = 0; j < KNN; ++j) o[j] = (u16)(fi[j] & (NPTS - 1));
  }
}

__global__ __launch_bounds__(256)
void k_out_nb(const float* __restrict__ x, const u16* __restrict__ nn,
              const float* __restrict__ dinv,
              const float* __restrict__ W0, const float* __restrict__ W1,
              const float* __restrict__ bias, float* __restrict__ out) {
  __shared__ float w0[CH * CH], w1[CH * CH], bs[CH];
  for (int i = threadIdx.x; i < CH * CH; i += 256) { w0[i] = W0[i]; w1[i] = W1[i]; }
  if (threadIdx.x < CH) bs[threadIdx.x] = bias[threadIdx.x];
  __syncthreads();
  int node = blockIdx.x * 256 + threadIdx.x;
  int b = node >> 12, n = node & (NPTS - 1);
  const float* xb = x + (size_t)b * CH * NPTS;
  float f[CH], acc[CH], tx[CH];
#pragma unroll
  for (int c = 0; c < CH; ++c) f[c] = xb[(size_t)c * NPTS + n];
#pragma unroll
  for (int o = 0; o < CH; ++o) acc[o] = bs[o];
#pragma unroll
  for (int c = 0; c < CH; ++c) {
    float fc = f[c];
    const float* wr = w0 + c * CH;
#pragma unroll
    for (int o = 0; o < CH; ++o) acc[o] += fc * wr[o];
  }
#pragma unroll
  for (int c = 0; c < CH; ++c) tx[c] = 0.f;
  float dn = dinv[node];
  int jmax = (node == NBN - 1) ? (KNN - 1) : KNN;
  for (int j = 0; j < jmax; ++j) {
    int s = nn[(size_t)node * KNN + j] & (NPTS - 1);
    float w = -(dinv[(b << 12) + s] * dn);
#pragma unroll
    for (int c = 0; c < CH; ++c) tx[c] += w * xb[(size_t)c * NPTS + s];
  }
#pragma unroll
  for (int c = 0; c < CH; ++c) {
    float tc = tx[c];
    const float* wr = w1 + c * CH;
#pragma unroll
    for (int o = 0; o < CH; ++o) acc[o] += tc * wr[o];
  }
  float4* op = (float4*)(out + (size_t)node * CH);
#pragma unroll
  for (int i = 0; i < CH / 4; ++i)
    op[i] = make_float4(acc[4*i], acc[4*i+1], acc[4*i+2], acc[4*i+3]);
}

extern "C" void kernel_launch(void* const* d_in, const int* in_sizes, int n_in,
                              void* d_out, int out_size, void* d_ws, size_t ws_size,
                              hipStream_t stream) {
  const float* x    = (const float*)d_in[0];
  const float* W0   = (const float*)d_in[1];
  const float* W1   = (const float*)d_in[2];
  const float* bias = (const float*)d_in[3];
  float* out = (float*)d_out;
  char* w = (char*)d_ws;

  const size_t SZ_XN   = (size_t)NBN * CH * 4;            //  6,291,456
  const size_t SZ_XRAW = (size_t)NBN * CH * 4;            //  6,291,456
  const size_t SZ_CSQ  = (size_t)NBN * 4;                 //    131,072
  const size_t SZ_NN   = (size_t)NBN * KNN * 2;           //    589,824
  const size_t SZ_DEG  = (size_t)NBN * 4;                 //    131,072
  const size_t SZ_AB   = (size_t)NBN * 128 * 2;           //  8,388,608
  const size_t SZ_CU   = (size_t)NBN * 16 * NCAND * 8;    // 50,331,648
  const size_t SZ_C12  = (size_t)NBN * NCAND * 4;         //  1,572,864
  const size_t needF = SZ_XN + SZ_XRAW + SZ_CSQ + SZ_NN + SZ_DEG
                     + 2 * SZ_AB + SZ_CU + SZ_C12;        // ~82.1 MB

  if (ws_size >= needF) {          // FAST path: MFMA filter + reduce + rescore
    size_t off = 0;
    float* xn   = (float*)(w + off); off += SZ_XN;
    float* xraw = (float*)(w + off); off += SZ_XRAW;
    float* csq  = (float*)(w + off); off += SZ_CSQ;
    u16*   nn   = (u16*)  (w + off); off += SZ_NN;
    int*   deg  = (int*)  (w + off); off += SZ_DEG;
    u16*   Abuf = (u16*)  (w + off); off += SZ_AB;
    u16*   Bbuf = (u16*)  (w + off); off += SZ_AB;
    u64*   candu= (u64*)  (w + off); off += SZ_CU;
    u32*   cand12=(u32*)  (w + off);
    k_prep    <<<NBN / 256, 256, 0, stream>>>(x, xraw, xn, csq, Abuf, Bbuf, deg);
    k_knn_m   <<<dim3(NBN / 64, 4), 256, 0, stream>>>(Abuf, Bbuf, candu);
    k_reduce  <<<NBN / 64, 256, 0, stream>>>(candu, cand12);
    k_rescore <<<NBN / RR, 256, 0, stream>>>(xn, csq, cand12, nn, deg);
    k_out_f   <<<NBN / ONB, 256, 0, stream>>>(xraw, nn, deg, W0, W1, bias, out);
  } else {                         // FALLBACK: proven round-4 path (852 KB)
    u16*   nn   = (u16*)w;
    int*   deg  = (int*)(w + SZ_NN);
    float* dinv = (float*)(w + SZ_NN + SZ_DEG);
    k_knn_nb <<<NBN / RPB, 256, 0, stream>>>(x, nn);
    k_zero   <<<NBN / 256, 256, 0, stream>>>(deg);
    k_hist   <<<NBN / 256, 256, 0, stream>>>(nn, deg);
    k_dinv   <<<NBN / 256, 256, 0, stream>>>(deg, dinv);
    k_out_nb <<<NBN / 256, 256, 0, stream>>>(x, nn, dinv, W0, W1, bias, out);
  }
}